// Round 7
// baseline (1847.312 us; speedup 1.0000x reference)
//
#include <hip/hip_runtime.h>
#include <math.h>

#define Bb 64
#define Ss 64
#define Hh 1024
#define Vv 32000
#define RD 4032     // 63*64 decoder rows
#define RP 4096     // padded rows
#define NT4 4096    // 4*H
#define ENC_NBLK 64
#define SENT 0xFFFFFFFFFFFFFFFFULL

typedef unsigned short u16;
typedef unsigned long long u64;
typedef __attribute__((ext_vector_type(8))) short bf16x8;
typedef __attribute__((ext_vector_type(4))) float f32x4;

#define MFMA(a, b, c) __builtin_amdgcn_mfma_f32_16x16x32_bf16(a, b, c, 0, 0, 0)

__device__ __forceinline__ u16 f2b(float f) {
  union { float f; unsigned u; } v; v.f = f;
  unsigned r = v.u + 0x7fffu + ((v.u >> 16) & 1u);
  return (u16)(r >> 16);
}
__device__ __forceinline__ float b2f(u16 b) {
  union { unsigned u; float f; } v; v.u = ((unsigned)b) << 16; return v.f;
}
__device__ __forceinline__ float sigf(float x) { return 1.f / (1.f + expf(-x)); }

__device__ __forceinline__ u64 AL(const u64* p) {
  return __hip_atomic_load(p, __ATOMIC_RELAXED, __HIP_MEMORY_SCOPE_AGENT);
}
__device__ __forceinline__ void AS(u64* p, u64 v) {
  __hip_atomic_store(p, v, __ATOMIC_RELAXED, __HIP_MEMORY_SCOPE_AGENT);
}

__device__ __forceinline__ void gll16(const void* g, void* l) {
  __builtin_amdgcn_global_load_lds(
      (const __attribute__((address_space(1))) unsigned int*)g,
      (__attribute__((address_space(3))) unsigned int*)l, 16, 0, 0);
}

__global__ void k_fail(float* out) { out[0] = 1e30f; }

// ---- f32 -> bf16 convert (vector4) ----
__global__ void k_cvt(const float* __restrict__ in, u16* __restrict__ out, int n4) {
  int i = blockIdx.x * blockDim.x + threadIdx.x;
  const int st = gridDim.x * blockDim.x;
  for (; i < n4; i += st) {
    float4 v = ((const float4*)in)[i];
    ushort4 o; o.x = f2b(v.x); o.y = f2b(v.y); o.z = f2b(v.z); o.w = f2b(v.w);
    ((ushort4*)out)[i] = o;
  }
}

// ---- embedding gather -> bf16 rows (row r = step*64 + b) ----
__global__ void k_gather(const int* __restrict__ tok, const float* __restrict__ emb,
                         u16* __restrict__ outp, int nstep) {
  const int r = blockIdx.x;
  const int step = r >> 6, b = r & 63;
  const int idx = (step < nstep) ? tok[b * 64 + step] : 0;
  const float4 v = ((const float4*)(emb + (size_t)idx * Hh))[threadIdx.x];
  ushort4 o; o.x = f2b(v.x); o.y = f2b(v.y); o.z = f2b(v.z); o.w = f2b(v.w);
  ((ushort4*)(outp + (size_t)r * Hh))[threadIdx.x] = o;
}

// ---- shared device GEMM tile: C_bf16[RP x NT4] = A[RP x Hh] @ B[NT4 x Hh]^T
__device__ __forceinline__ void dg_tile(const u16* __restrict__ A, const u16* __restrict__ Bm,
                                        u16* __restrict__ C, int bx, int by,
                                        u16* As, u16* Bs) {
  const int tid = threadIdx.x;
  const int wave = tid >> 6, lane = tid & 63;
  const int l15 = lane & 15, lhi = lane >> 4;
  const int m0 = by * 128, n0 = bx * 128;
  const int wm = (wave >> 1) * 64, wn = (wave & 1) * 64;
  f32x4 acc[4][4] = {};
  const int srow = wave * 32 + (lane >> 3);
  const int scolb = (lane & 7) * 16;
  for (int k0 = 0; k0 < Hh; k0 += 64) {
    __syncthreads();
#pragma unroll
    for (int q = 0; q < 4; ++q) {
      const int r = srow + q * 8;
      gll16((const char*)(A + (size_t)(m0 + r) * Hh + k0) + scolb,
            (char*)As + (wave * 32 + q * 8) * 128);
      gll16((const char*)(Bm + (size_t)(n0 + r) * Hh + k0) + scolb,
            (char*)Bs + (wave * 32 + q * 8) * 128);
    }
    __syncthreads();
#pragma unroll
    for (int kk = 0; kk < 2; ++kk) {
      const int ko = kk * 32 + lhi * 8;
      bf16x8 af[4], bfr[4];
#pragma unroll
      for (int i = 0; i < 4; ++i) af[i] = *(const bf16x8*)(As + (wm + i * 16 + l15) * 64 + ko);
#pragma unroll
      for (int j = 0; j < 4; ++j) bfr[j] = *(const bf16x8*)(Bs + (wn + j * 16 + l15) * 64 + ko);
#pragma unroll
      for (int i = 0; i < 4; ++i)
#pragma unroll
        for (int j = 0; j < 4; ++j)
          acc[i][j] = MFMA(af[i], bfr[j], acc[i][j]);
    }
  }
#pragma unroll
  for (int i = 0; i < 4; ++i) {
    const int gr = m0 + wm + i * 16 + lhi * 4;
#pragma unroll
    for (int j = 0; j < 4; ++j) {
      const int gc = n0 + wn + j * 16 + l15;
#pragma unroll
      for (int rr = 0; rr < 4; ++rr)
        C[(size_t)(gr + rr) * NT4 + gc] = f2b(acc[i][j][rr]);
    }
  }
}

// ---- standalone pre-GEMM (bf16 out): encoder x-gates ----
__global__ __launch_bounds__(256)
void k_pre(const u16* __restrict__ A, const u16* __restrict__ Bm, u16* __restrict__ C) {
  __shared__ __align__(16) u16 As[128 * 64];
  __shared__ __align__(16) u16 Bs[128 * 64];
  const int t = blockIdx.x;
  dg_tile(A, Bm, C, t & 31, t >> 5, As, Bs);
}

// ---- generic bf16 MFMA GEMM with epilogues.
// EPI==0: fp32 C (+bias).  EPI==3: bf16 C = tanh(acc+bias).
// EPI==2: fused per-row (max,sumexp) partials per 64-col half-tile.
template<int EPI>
__global__ __launch_bounds__(256)
void k_gemm(const u16* __restrict__ A, const u16* __restrict__ Bm,
            void* __restrict__ C, int M, int N, int K,
            const float* __restrict__ bias,
            float* __restrict__ pmax, float* __restrict__ psum, int ncols) {
  __shared__ __align__(16) u16 As[128 * 64];
  __shared__ __align__(16) u16 Bs[128 * 64];
  const int tid = threadIdx.x;
  const int wave = tid >> 6, lane = tid & 63;
  const int l15 = lane & 15, lhi = lane >> 4;
  int bx = blockIdx.x, by = blockIdx.y;
  {
    const int gx_ = gridDim.x, gy_ = gridDim.y;
    const int nwg = gx_ * gy_;
    if ((gy_ & 3) == 0 && (gx_ & 1) == 0) {
      const int f = by * gx_ + bx;
      const int x = f & 7, i = f >> 3;
      const int rby = gy_ >> 2, hx = gx_ >> 1;
      by = (x >> 1) * rby + (i % rby);
      bx = (x & 1) * hx + (i / rby);
    } else if ((nwg & 7) == 0) {
      int flat = by * gx_ + bx;
      const int qq = nwg >> 3;
      flat = (flat & 7) * qq + (flat >> 3);
      bx = flat % gx_; by = flat / gx_;
    }
  }
  const int m0 = by * 128, n0 = bx * 128;
  const int wm = (wave >> 1) * 64, wn = (wave & 1) * 64;
  f32x4 acc[4][4] = {};
  const int srow = wave * 32 + (lane >> 3);
  const int scolb = (lane & 7) * 16;

  for (int k0 = 0; k0 < K; k0 += 64) {
    __syncthreads();
#pragma unroll
    for (int q = 0; q < 4; ++q) {
      const int r = srow + q * 8;
      int ra = m0 + r; ra = (ra < M) ? ra : (M - 1);
      gll16((const char*)(A + (size_t)ra * K + k0) + scolb,
            (char*)As + (wave * 32 + q * 8) * 128);
      gll16((const char*)(Bm + (size_t)(n0 + r) * K + k0) + scolb,
            (char*)Bs + (wave * 32 + q * 8) * 128);
    }
    __syncthreads();
#pragma unroll
    for (int kk = 0; kk < 2; ++kk) {
      const int ko = kk * 32 + lhi * 8;
      bf16x8 af[4], bfr[4];
#pragma unroll
      for (int i = 0; i < 4; ++i) af[i] = *(const bf16x8*)(As + (wm + i * 16 + l15) * 64 + ko);
#pragma unroll
      for (int j = 0; j < 4; ++j) bfr[j] = *(const bf16x8*)(Bs + (wn + j * 16 + l15) * 64 + ko);
#pragma unroll
      for (int i = 0; i < 4; ++i)
#pragma unroll
        for (int j = 0; j < 4; ++j)
          acc[i][j] = MFMA(af[i], bfr[j], acc[i][j]);
    }
  }

  if (EPI == 0) {
#pragma unroll
    for (int i = 0; i < 4; ++i) {
      const int gr = m0 + wm + i * 16 + lhi * 4;
#pragma unroll
      for (int j = 0; j < 4; ++j) {
        const int gc = n0 + wn + j * 16 + l15;
        const float bv = bias ? bias[gc] : 0.f;
#pragma unroll
        for (int rr = 0; rr < 4; ++rr)
          ((float*)C)[(size_t)(gr + rr) * N + gc] = acc[i][j][rr] + bv;
      }
    }
  } else if (EPI == 3) {
#pragma unroll
    for (int i = 0; i < 4; ++i) {
      const int gr = m0 + wm + i * 16 + lhi * 4;
#pragma unroll
      for (int j = 0; j < 4; ++j) {
        const int gc = n0 + wn + j * 16 + l15;
        const float bv = bias[gc];
#pragma unroll
        for (int rr = 0; rr < 4; ++rr)
          ((u16*)C)[(size_t)(gr + rr) * N + gc] = f2b(tanhf(acc[i][j][rr] + bv));
      }
    }
  } else {
    float bj[4];
#pragma unroll
    for (int j = 0; j < 4; ++j) bj[j] = bias[n0 + wn + j * 16 + l15];
    const int pc = bx * 2 + (wn ? 1 : 0);
#pragma unroll
    for (int i = 0; i < 4; ++i) {
#pragma unroll
      for (int rr = 0; rr < 4; ++rr) {
        float v0 = acc[i][0][rr] + bj[0];
        float v1 = acc[i][1][rr] + bj[1];
        float v2 = acc[i][2][rr] + bj[2];
        float v3 = acc[i][3][rr] + bj[3];
        float m = fmaxf(fmaxf(v0, v1), fmaxf(v2, v3));
#pragma unroll
        for (int d = 1; d < 16; d <<= 1) m = fmaxf(m, __shfl_xor(m, d, 64));
        float s = __expf(v0 - m) + __expf(v1 - m) + __expf(v2 - m) + __expf(v3 - m);
#pragma unroll
        for (int d = 1; d < 16; d <<= 1) s += __shfl_xor(s, d, 64);
        if (l15 == 0) {
          const int grow = m0 + wm + i * 16 + lhi * 4 + rr;
          pmax[(size_t)grow * ncols + pc] = m;
          psum[(size_t)grow * ncols + pc] = s;
        }
      }
    }
  }
}

// ---- fused persistent encoder + co-scheduled decoder pre-GEMM.
// Blocks 0..63: LSTM recurrence, block owns 16 h-cols. Sentinel dataflow:
// hxl pre-filled 0xFF (bf16 NaN, unreachable); producers store h via relaxed
// agent atomics (write-through); consumers issue optimistic bulk loads at END
// of previous step (overlap own store drain), then bulk patch rounds (reload
// only sentinels, parallel per round). No flags, no fences.
// Blocks 64..1087: decoder pre-GEMM tiles (gates_dec), LDS aliased.
__global__ __launch_bounds__(256, 1)
void k_enc_fused(const u16* __restrict__ Wb, const u16* __restrict__ gx,
                 const float* __restrict__ b_ih, const float* __restrict__ b_hh,
                 u16* __restrict__ hxl, float* __restrict__ c_out,
                 const u16* __restrict__ Adec, const u16* __restrict__ Bdec,
                 u16* __restrict__ Cdec) {
  __shared__ __align__(16) char LB[64 * 2048 + 64 * 65 * 4 + 256];
  const int tid = threadIdx.x;

  if (blockIdx.x >= ENC_NBLK) {
    const int t = blockIdx.x - ENC_NBLK;
    dg_tile(Adec, Bdec, Cdec, t & 31, t >> 5, (u16*)LB, (u16*)(LB + 16384));
    return;
  }

  u16* Ws = (u16*)LB;                               // 128 KB, XOR-swizzled
  float* Gs = (float*)(LB + 131072);                // [64][65]
  float* bsum = (float*)(LB + 131072 + 64 * 65 * 4);
  const int wave = tid >> 6, lane = tid & 63;
  const int l15 = lane & 15, lhi = lane >> 4;
  const int c0 = blockIdx.x * 16;
  const int cb = tid >> 2, cq = tid & 3;
  const int rot = blockIdx.x & 31;

  for (int i = tid; i < 64 * 128; i += 256) {
    const int r = i >> 7, ck = i & 127;
    const int grow = (r >> 4) * Hh + c0 + (r & 15);
    const int bo = (ck * 16) ^ ((r & 7) << 4);
    *(bf16x8*)((char*)Ws + r * 2048 + bo) = *(const bf16x8*)(Wb + (size_t)grow * Hh + ck * 8);
  }
  if (tid < 64) {
    const int col = (tid >> 4) * Hh + c0 + (tid & 15);
    bsum[tid] = b_ih[col] + b_hh[col];
  }
  float creg[4] = {0.f, 0.f, 0.f, 0.f};
  __syncthreads();

  u64 ha[32], hb[32];
  for (int s = 0; s < 64; ++s) {
    // x-gates (bf16, 4 per gate)
    u64 graw[4];
#pragma unroll
    for (int g = 0; g < 4; ++g)
      graw[g] = *(const u64*)(gx + (size_t)(s * 64 + cb) * NT4 + g * Hh + c0 + cq * 4);

    f32x4 acc[4] = {};
    if (s > 0) {
      const u64* apw = (const u64*)(hxl + ((size_t)(s - 1) * 64 + wave * 16 + l15) * Hh);
      // bulk patch rounds: reload only sentinel entries, parallel per round
      for (;;) {
        bool any = false;
#pragma unroll
        for (int i = 0; i < 32; ++i) {
          const int kw = ((i + rot) & 31) * 8 + lhi * 2;
          if (ha[i] == SENT) { ha[i] = AL(apw + kw); any = true; }
          if (hb[i] == SENT) { hb[i] = AL(apw + kw + 1); any = true; }
        }
        if (!__any(any)) break;
        __builtin_amdgcn_s_sleep(1);
      }
      const char* wsb = (const char*)Ws;
      const int xr = (l15 & 7) << 4;
#pragma unroll
      for (int i = 0; i < 32; ++i) {
        const int kf = (i + rot) & 31;
        union { u64 q[2]; bf16x8 v; } cv;
        cv.q[0] = ha[i]; cv.q[1] = hb[i];
        const int kb = ((kf * 32 + lhi * 8) * 2) ^ xr;
#pragma unroll
        for (int nt = 0; nt < 4; ++nt)
          acc[nt] = MFMA(cv.v, *(const bf16x8*)(wsb + (nt * 16 + l15) * 2048 + kb), acc[nt]);
      }
    }
#pragma unroll
    for (int nt = 0; nt < 4; ++nt)
#pragma unroll
      for (int r = 0; r < 4; ++r)
        Gs[(wave * 16 + lhi * 4 + r) * 65 + nt * 16 + l15] = acc[nt][r];
    __syncthreads();
    {
      const float* gsrow = Gs + cb * 65;
      u64 pk = 0;
#pragma unroll
      for (int j = 0; j < 4; ++j) {
        const int col = cq * 4 + j;
        const float gi = gsrow[col]      + b2f((u16)(graw[0] >> (16 * j))) + bsum[col];
        const float gf = gsrow[16 + col] + b2f((u16)(graw[1] >> (16 * j))) + bsum[16 + col];
        const float gg = gsrow[32 + col] + b2f((u16)(graw[2] >> (16 * j))) + bsum[32 + col];
        const float go = gsrow[48 + col] + b2f((u16)(graw[3] >> (16 * j))) + bsum[48 + col];
        const float cn = sigf(gf) * creg[j] + sigf(gi) * tanhf(gg);
        const float hv = sigf(go) * tanhf(cn);
        creg[j] = cn;
        pk |= (u64)f2b(hv) << (16 * j);
      }
      AS((u64*)(hxl + ((size_t)s * 64 + cb) * Hh + c0 + cq * 4), pk);
    }
    // optimistic bulk loads for next step (overlap our store drain at barrier)
    if (s < 63) {
      const u64* apn = (const u64*)(hxl + ((size_t)s * 64 + wave * 16 + l15) * Hh);
#pragma unroll
      for (int i = 0; i < 32; ++i) {
        const int kw = ((i + rot) & 31) * 8 + lhi * 2;
        ha[i] = AL(apn + kw);
        hb[i] = AL(apn + kw + 1);
      }
    }
    __syncthreads();  // Gs WAR; also drains store + optimistic loads together
  }
#pragma unroll
  for (int j = 0; j < 4; ++j)
    c_out[cb * Hh + c0 + cq * 4 + j] = creg[j];
}

// ---- decoder cell (vectorized x4): gates = G_bf16[r] + dbase[b] + b_ih + b_hh
__global__ void k_dec_cell(const u16* __restrict__ G, const float* __restrict__ dbase,
                           const float* __restrict__ cT, const float* __restrict__ b_ih,
                           const float* __restrict__ b_hh, u16* __restrict__ Acat) {
  const int idx = blockIdx.x * 256 + threadIdx.x;
  const int r = idx >> 8, c4 = (idx & 255) * 4;
  if (r >= RD) return;
  const int b = r & 63;
  u64 graw[4]; f32x4 dv[4], bi[4], bh[4];
#pragma unroll
  for (int g = 0; g < 4; ++g) {
    graw[g] = *(const u64*)(G + (size_t)r * NT4 + g * Hh + c4);
    dv[g] = *(const f32x4*)(dbase + (size_t)b * NT4 + g * Hh + c4);
    bi[g] = *(const f32x4*)(b_ih + g * Hh + c4);
    bh[g] = *(const f32x4*)(b_hh + g * Hh + c4);
  }
  const f32x4 cv4 = *(const f32x4*)(cT + b * Hh + c4);
  u64 pk = 0;
#pragma unroll
  for (int j = 0; j < 4; ++j) {
    const float gi = b2f((u16)(graw[0] >> (16 * j))) + dv[0][j] + bi[0][j] + bh[0][j];
    const float gf = b2f((u16)(graw[1] >> (16 * j))) + dv[1][j] + bi[1][j] + bh[1][j];
    const float gg = b2f((u16)(graw[2] >> (16 * j))) + dv[2][j] + bi[2][j] + bh[2][j];
    const float go = b2f((u16)(graw[3] >> (16 * j))) + dv[3][j] + bi[3][j] + bh[3][j];
    const float cn = sigf(gf) * cv4[j] + sigf(gi) * tanhf(gg);
    const float hv = sigf(go) * tanhf(cn);
    pk |= (u64)f2b(hv) << (16 * j);
  }
  *(u64*)(Acat + (size_t)r * 2048 + Hh + c4) = pk;
}

// ---- fused attention per (t,b): scores + masked softmax + content -> A_cat[:, :H]
__global__ __launch_bounds__(256)
void k_attn(u16* Acat, const u16* __restrict__ hxl, const int* __restrict__ src) {
  __shared__ float qs[Hh];
  __shared__ float sc[Ss];
  const int r = blockIdx.x;
  const int b = r & 63;
  const int tid = threadIdx.x, wave = tid >> 6, lane = tid & 63;
  for (int h = tid; h < Hh; h += 256) qs[h] = b2f(Acat[(size_t)r * 2048 + Hh + h]);
  __syncthreads();
  for (int sub = 0; sub < 16; ++sub) {
    const int ss = wave * 16 + sub;
    const ushort4* hp4 = (const ushort4*)(hxl + ((size_t)ss * Bb + b) * Hh);
    float p = 0.f;
#pragma unroll
    for (int q = 0; q < 4; ++q) {
      const int i4 = lane + 64 * q;
      const ushort4 v = hp4[i4];
      p += qs[i4 * 4 + 0] * b2f(v.x) + qs[i4 * 4 + 1] * b2f(v.y)
         + qs[i4 * 4 + 2] * b2f(v.z) + qs[i4 * 4 + 3] * b2f(v.w);
    }
#pragma unroll
    for (int d = 1; d < 64; d <<= 1) p += __shfl_xor(p, d, 64);
    if (lane == 0) sc[ss] = (src[b * 64 + ss] != 0) ? p : -INFINITY;
  }
  __syncthreads();
  if (wave == 0) {
    const float v = sc[lane];
    float m = v;
#pragma unroll
    for (int d = 1; d < 64; d <<= 1) m = fmaxf(m, __shfl_xor(m, d, 64));
    const float e = __expf(v - m);
    float ssum = e;
#pragma unroll
    for (int d = 1; d < 64; d <<= 1) ssum += __shfl_xor(ssum, d, 64);
    sc[lane] = e / ssum;
  }
  __syncthreads();
  float4 a4 = {0.f, 0.f, 0.f, 0.f};
  for (int s2 = 0; s2 < 64; ++s2) {
    const float a = sc[s2];
    const ushort4 v = *(const ushort4*)(hxl + ((size_t)s2 * Bb + b) * Hh + tid * 4);
    a4.x += a * b2f(v.x); a4.y += a * b2f(v.y);
    a4.z += a * b2f(v.z); a4.w += a * b2f(v.w);
  }
  u16* dst = Acat + (size_t)r * 2048 + tid * 4;
  dst[0] = f2b(a4.x); dst[1] = f2b(a4.y); dst[2] = f2b(a4.z); dst[3] = f2b(a4.w);
}

// ---- combine lse partials: one wave per row
__global__ void k_lse(const float* __restrict__ pmax, const float* __restrict__ psum,
                      float* __restrict__ lse, int ncols) {
  const int r = blockIdx.x * 4 + (threadIdx.x >> 6);
  const int lane = threadIdx.x & 63;
  if (r >= RD) return;
  float m = -INFINITY;
  for (int i = lane; i < ncols; i += 64) m = fmaxf(m, pmax[(size_t)r * ncols + i]);
#pragma unroll
  for (int d = 1; d < 64; d <<= 1) m = fmaxf(m, __shfl_xor(m, d, 64));
  float s = 0.f;
  for (int i = lane; i < ncols; i += 64)
    s += psum[(size_t)r * ncols + i] * __expf(pmax[(size_t)r * ncols + i] - m);
#pragma unroll
  for (int d = 1; d < 64; d <<= 1) s += __shfl_xor(s, d, 64);
  if (lane == 0) lse[r] = m + logf(s);
}

// ---- target logit: one wave per row (bf16 a x fp32 W)
__global__ void k_tlogit(const u16* __restrict__ hx_att_b, const int* __restrict__ target,
                         const float* __restrict__ W, const float* __restrict__ bo,
                         float* __restrict__ outp) {
  const int r = blockIdx.x * 4 + (threadIdx.x >> 6);
  const int lane = threadIdx.x & 63;
  if (r >= RD) return;
  const int t = r >> 6, b = r & 63;
  const int w = target[b * 64 + t + 1];
  const u16* a = hx_att_b + (size_t)r * Hh;
  const float* wr = W + (size_t)w * Hh;
  float p = 0.f;
  for (int h = lane; h < Hh; h += 64) p += b2f(a[h]) * wr[h];
#pragma unroll
  for (int d = 1; d < 64; d <<= 1) p += __shfl_xor(p, d, 64);
  if (lane == 0) outp[r] = p + bo[w];
}

// ---- final reduction -> scalar loss
__global__ void k_final(const float* __restrict__ lse, const float* __restrict__ tl,
                        const int* __restrict__ target, float* __restrict__ out) {
  const int t = threadIdx.x;
  float ps = 0.f;
  if (t < 63) {
    float sn = 0.f, cnt = 0.f;
    for (int b = 0; b < 64; ++b) {
      const int r = t * 64 + b;
      const int w = target[b * 64 + t + 1];
      if (w != 0) { sn += lse[r] - tl[r]; cnt += 1.f; }
    }
    ps = sn / fmaxf(cnt, 1.f);
  }
#pragma unroll
  for (int d = 1; d < 64; d <<= 1) ps += __shfl_xor(ps, d, 64);
  if (t == 0) out[0] = ps;
}

extern "C" void kernel_launch(void* const* d_in, const int* in_sizes, int n_in,
                              void* d_out, int out_size, void* d_ws, size_t ws_size,
                              hipStream_t stream) {
  const int*   source   = (const int*)d_in[0];
  const int*   target   = (const int*)d_in[1];
  const float* emb_src  = (const float*)d_in[2];
  const float* emb_tgt  = (const float*)d_in[3];
  const float* W_ih_enc = (const float*)d_in[4];
  const float* W_hh_enc = (const float*)d_in[5];
  const float* b_ih_enc = (const float*)d_in[6];
  const float* b_hh_enc = (const float*)d_in[7];
  const float* W_ih_dec = (const float*)d_in[8];
  const float* W_hh_dec = (const float*)d_in[9];
  const float* b_ih_dec = (const float*)d_in[10];
  const float* b_hh_dec = (const float*)d_in[11];
  const float* W_att    = (const float*)d_in[12];
  const float* b_att    = (const float*)d_in[13];
  const float* W_out    = (const float*)d_in[14];
  const float* b_out    = (const float*)d_in[15];
  float* out = (float*)d_out;

  char* base = (char*)d_ws;
  size_t off = 0;
  auto alloc = [&](size_t bytes) -> void* {
    void* r = base + off; off += (bytes + 255) & ~(size_t)255; return r;
  };
  u16*   wb_ih_enc = (u16*)alloc((size_t)NT4 * Hh * 2);
  u16*   wb_hh_enc = (u16*)alloc((size_t)NT4 * Hh * 2);
  u16*   wb_ih_dec = (u16*)alloc((size_t)NT4 * Hh * 2);
  u16*   wb_hh_dec = (u16*)alloc((size_t)NT4 * Hh * 2);
  u16*   wb_att    = (u16*)alloc((size_t)Hh * 2048 * 2);
  u16*   wb_out    = (u16*)alloc((size_t)Vv * Hh * 2);
  u16*   x_src_b   = (u16*)alloc((size_t)RP * Hh * 2);
  u16*   x_dec_b   = (u16*)alloc((size_t)RP * Hh * 2);
  u16*   gates16   = (u16*)alloc((size_t)RP * NT4 * 2);
  u16*   gates_dec = (u16*)alloc((size_t)RP * NT4 * 2);
  u16*   hxl       = (u16*)alloc((size_t)Ss * Bb * Hh * 2);
  float* c_enc     = (float*)alloc((size_t)Bb * Hh * 4);
  float* dbase     = (float*)alloc((size_t)64 * NT4 * 4);
  u16*   Acat      = (u16*)alloc((size_t)RP * 2048 * 2);
  u16*   hx_att_b  = (u16*)alloc((size_t)RP * Hh * 2);
  float* pmax      = (float*)alloc((size_t)RP * 500 * 4);
  float* psum      = (float*)alloc((size_t)RP * 500 * 4);
  float* lse       = (float*)alloc((size_t)RD * 4);
  float* tlog      = (float*)alloc((size_t)RD * 4);

  if (off > ws_size) { k_fail<<<1, 1, 0, stream>>>(out); return; }

  // weights -> bf16
  k_cvt<<<2048, 256, 0, stream>>>(W_ih_enc, wb_ih_enc, NT4 * Hh / 4);
  k_cvt<<<2048, 256, 0, stream>>>(W_hh_enc, wb_hh_enc, NT4 * Hh / 4);
  k_cvt<<<2048, 256, 0, stream>>>(W_ih_dec, wb_ih_dec, NT4 * Hh / 4);
  k_cvt<<<2048, 256, 0, stream>>>(W_hh_dec, wb_hh_dec, NT4 * Hh / 4);
  k_cvt<<<2048, 256, 0, stream>>>(W_att, wb_att, Hh * 2048 / 4);
  k_cvt<<<2048, 256, 0, stream>>>(W_out, wb_out, Vv * Hh / 4);

  // sentinel fill for dataflow encoder
  hipMemsetAsync(hxl, 0xFF, (size_t)Ss * Bb * Hh * 2, stream);

  // embedding gathers
  k_gather<<<RP, 256, 0, stream>>>(source, emb_src, x_src_b, 64);
  k_gather<<<RP, 256, 0, stream>>>(target, emb_tgt, x_dec_b, 63);

  // encoder x-gates pre-GEMM (bf16 out)
  k_pre<<<1024, 256, 0, stream>>>(x_src_b, wb_ih_enc, gates16);

  // fused: persistent encoder (blocks 0..63) + decoder pre-GEMM (blocks 64..1087)
  k_enc_fused<<<ENC_NBLK + 1024, 256, 0, stream>>>(wb_hh_enc, gates16, b_ih_enc, b_hh_enc,
                                                   hxl, c_enc, x_dec_b, wb_ih_dec, gates_dec);

  // hT base + decoder cell
  k_gemm<0><<<dim3(32, 1), 256, 0, stream>>>(hxl + (size_t)63 * Bb * Hh, wb_hh_dec, dbase,
                                             64, NT4, Hh, nullptr, nullptr, nullptr, 0);
  k_dec_cell<<<RD, 256, 0, stream>>>(gates_dec, dbase, c_enc, b_ih_dec, b_hh_dec, Acat);

  // attention -> content into A_cat[:, :H]
  k_attn<<<RD, 256, 0, stream>>>(Acat, hxl, source);

  // hx_att_b = bf16(tanh(A_cat @ W_att^T + b_att))
  k_gemm<3><<<dim3(8, 32), 256, 0, stream>>>(Acat, wb_att, hx_att_b, RP, Hh, 2048,
                                             b_att, nullptr, nullptr, 0);

  // vocab GEMM with fused lse partials
  k_gemm<2><<<dim3(250, 32), 256, 0, stream>>>(hx_att_b, wb_out, nullptr, RP, Vv, Hh,
                                               b_out, pmax, psum, 500);
  k_lse<<<(RD + 3) / 4, 256, 0, stream>>>(pmax, psum, lse, 500);
  k_tlogit<<<(RD + 3) / 4, 256, 0, stream>>>(hx_att_b, target, W_out, b_out, tlog);
  k_final<<<1, 64, 0, stream>>>(lse, tlog, target, out);
}

// Round 8
// 1521.804 us; speedup vs baseline: 1.2139x; 1.2139x over previous
//
#include <hip/hip_runtime.h>
#include <math.h>

#define Bb 64
#define Ss 64
#define Hh 1024
#define Vv 32000
#define RD 4032     // 63*64 decoder rows
#define RP 4096     // padded rows
#define NT4 4096    // 4*H
#define ENC_NBLK 64

typedef unsigned short u16;
typedef unsigned long long u64;
typedef __attribute__((ext_vector_type(8))) short bf16x8;
typedef __attribute__((ext_vector_type(4))) float f32x4;

#define MFMA(a, b, c) __builtin_amdgcn_mfma_f32_16x16x32_bf16(a, b, c, 0, 0, 0)

__device__ __forceinline__ u16 f2b(float f) {
  union { float f; unsigned u; } v; v.f = f;
  unsigned r = v.u + 0x7fffu + ((v.u >> 16) & 1u);
  return (u16)(r >> 16);
}
__device__ __forceinline__ float b2f(u16 b) {
  union { unsigned u; float f; } v; v.u = ((unsigned)b) << 16; return v.f;
}
__device__ __forceinline__ float sigf(float x) { return 1.f / (1.f + expf(-x)); }

__device__ __forceinline__ u64 AL(const u64* p) {
  return __hip_atomic_load(p, __ATOMIC_RELAXED, __HIP_MEMORY_SCOPE_AGENT);
}
__device__ __forceinline__ void AS(u64* p, u64 v) {
  __hip_atomic_store(p, v, __ATOMIC_RELAXED, __HIP_MEMORY_SCOPE_AGENT);
}
__device__ __forceinline__ int AL32(const int* p) {
  return __hip_atomic_load(p, __ATOMIC_RELAXED, __HIP_MEMORY_SCOPE_AGENT);
}
__device__ __forceinline__ void AS32(int* p, int v) {
  __hip_atomic_store(p, v, __ATOMIC_RELAXED, __HIP_MEMORY_SCOPE_AGENT);
}

__device__ __forceinline__ void gll16(const void* g, void* l) {
  __builtin_amdgcn_global_load_lds(
      (const __attribute__((address_space(1))) unsigned int*)g,
      (__attribute__((address_space(3))) unsigned int*)l, 16, 0, 0);
}

__global__ void k_fail(float* out) { out[0] = 1e30f; }

// ---- f32 -> bf16 convert (vector4) ----
__global__ void k_cvt(const float* __restrict__ in, u16* __restrict__ out, int n4) {
  int i = blockIdx.x * blockDim.x + threadIdx.x;
  const int st = gridDim.x * blockDim.x;
  for (; i < n4; i += st) {
    float4 v = ((const float4*)in)[i];
    ushort4 o; o.x = f2b(v.x); o.y = f2b(v.y); o.z = f2b(v.z); o.w = f2b(v.w);
    ((ushort4*)out)[i] = o;
  }
}

// ---- embedding gather -> bf16 rows (row r = step*64 + b) ----
__global__ void k_gather(const int* __restrict__ tok, const float* __restrict__ emb,
                         u16* __restrict__ outp, int nstep) {
  const int r = blockIdx.x;
  const int step = r >> 6, b = r & 63;
  const int idx = (step < nstep) ? tok[b * 64 + step] : 0;
  const float4 v = ((const float4*)(emb + (size_t)idx * Hh))[threadIdx.x];
  ushort4 o; o.x = f2b(v.x); o.y = f2b(v.y); o.z = f2b(v.z); o.w = f2b(v.w);
  ((ushort4*)(outp + (size_t)r * Hh))[threadIdx.x] = o;
}

// ---- shared device GEMM tile: C_bf16[RP x NT4] = A[RP x Hh] @ B[NT4 x Hh]^T
__device__ __forceinline__ void dg_tile(const u16* __restrict__ A, const u16* __restrict__ Bm,
                                        u16* __restrict__ C, int bx, int by,
                                        u16* As, u16* Bs) {
  const int tid = threadIdx.x;
  const int wave = tid >> 6, lane = tid & 63;
  const int l15 = lane & 15, lhi = lane >> 4;
  const int m0 = by * 128, n0 = bx * 128;
  const int wm = (wave >> 1) * 64, wn = (wave & 1) * 64;
  f32x4 acc[4][4] = {};
  const int srow = wave * 32 + (lane >> 3);
  const int scolb = (lane & 7) * 16;
  for (int k0 = 0; k0 < Hh; k0 += 64) {
    __syncthreads();
#pragma unroll
    for (int q = 0; q < 4; ++q) {
      const int r = srow + q * 8;
      gll16((const char*)(A + (size_t)(m0 + r) * Hh + k0) + scolb,
            (char*)As + (wave * 32 + q * 8) * 128);
      gll16((const char*)(Bm + (size_t)(n0 + r) * Hh + k0) + scolb,
            (char*)Bs + (wave * 32 + q * 8) * 128);
    }
    __syncthreads();
#pragma unroll
    for (int kk = 0; kk < 2; ++kk) {
      const int ko = kk * 32 + lhi * 8;
      bf16x8 af[4], bfr[4];
#pragma unroll
      for (int i = 0; i < 4; ++i) af[i] = *(const bf16x8*)(As + (wm + i * 16 + l15) * 64 + ko);
#pragma unroll
      for (int j = 0; j < 4; ++j) bfr[j] = *(const bf16x8*)(Bs + (wn + j * 16 + l15) * 64 + ko);
#pragma unroll
      for (int i = 0; i < 4; ++i)
#pragma unroll
        for (int j = 0; j < 4; ++j)
          acc[i][j] = MFMA(af[i], bfr[j], acc[i][j]);
    }
  }
#pragma unroll
  for (int i = 0; i < 4; ++i) {
    const int gr = m0 + wm + i * 16 + lhi * 4;
#pragma unroll
    for (int j = 0; j < 4; ++j) {
      const int gc = n0 + wn + j * 16 + l15;
#pragma unroll
      for (int rr = 0; rr < 4; ++rr)
        C[(size_t)(gr + rr) * NT4 + gc] = f2b(acc[i][j][rr]);
    }
  }
}

// ---- pre-GEMM (bf16 out): x-gates for enc/dec ----
__global__ __launch_bounds__(256)
void k_pre(const u16* __restrict__ A, const u16* __restrict__ Bm, u16* __restrict__ C) {
  __shared__ __align__(16) u16 As[128 * 64];
  __shared__ __align__(16) u16 Bs[128 * 64];
  const int t = blockIdx.x;
  dg_tile(A, Bm, C, t & 31, t >> 5, As, Bs);
}

// ---- generic bf16 MFMA GEMM with epilogues.
// EPI==0: fp32 C (+bias).  EPI==3: bf16 C = tanh(acc+bias).
// EPI==2: fused per-row (max,sumexp) partials per 64-col half-tile.
template<int EPI>
__global__ __launch_bounds__(256)
void k_gemm(const u16* __restrict__ A, const u16* __restrict__ Bm,
            void* __restrict__ C, int M, int N, int K,
            const float* __restrict__ bias,
            float* __restrict__ pmax, float* __restrict__ psum, int ncols) {
  __shared__ __align__(16) u16 As[128 * 64];
  __shared__ __align__(16) u16 Bs[128 * 64];
  const int tid = threadIdx.x;
  const int wave = tid >> 6, lane = tid & 63;
  const int l15 = lane & 15, lhi = lane >> 4;
  int bx = blockIdx.x, by = blockIdx.y;
  {
    const int gx_ = gridDim.x, gy_ = gridDim.y;
    const int nwg = gx_ * gy_;
    if ((gy_ & 3) == 0 && (gx_ & 1) == 0) {
      const int f = by * gx_ + bx;
      const int x = f & 7, i = f >> 3;
      const int rby = gy_ >> 2, hx = gx_ >> 1;
      by = (x >> 1) * rby + (i % rby);
      bx = (x & 1) * hx + (i / rby);
    } else if ((nwg & 7) == 0) {
      int flat = by * gx_ + bx;
      const int qq = nwg >> 3;
      flat = (flat & 7) * qq + (flat >> 3);
      bx = flat % gx_; by = flat / gx_;
    }
  }
  const int m0 = by * 128, n0 = bx * 128;
  const int wm = (wave >> 1) * 64, wn = (wave & 1) * 64;
  f32x4 acc[4][4] = {};
  const int srow = wave * 32 + (lane >> 3);
  const int scolb = (lane & 7) * 16;

  for (int k0 = 0; k0 < K; k0 += 64) {
    __syncthreads();
#pragma unroll
    for (int q = 0; q < 4; ++q) {
      const int r = srow + q * 8;
      int ra = m0 + r; ra = (ra < M) ? ra : (M - 1);
      gll16((const char*)(A + (size_t)ra * K + k0) + scolb,
            (char*)As + (wave * 32 + q * 8) * 128);
      gll16((const char*)(Bm + (size_t)(n0 + r) * K + k0) + scolb,
            (char*)Bs + (wave * 32 + q * 8) * 128);
    }
    __syncthreads();
#pragma unroll
    for (int kk = 0; kk < 2; ++kk) {
      const int ko = kk * 32 + lhi * 8;
      bf16x8 af[4], bfr[4];
#pragma unroll
      for (int i = 0; i < 4; ++i) af[i] = *(const bf16x8*)(As + (wm + i * 16 + l15) * 64 + ko);
#pragma unroll
      for (int j = 0; j < 4; ++j) bfr[j] = *(const bf16x8*)(Bs + (wn + j * 16 + l15) * 64 + ko);
#pragma unroll
      for (int i = 0; i < 4; ++i)
#pragma unroll
        for (int j = 0; j < 4; ++j)
          acc[i][j] = MFMA(af[i], bfr[j], acc[i][j]);
    }
  }

  if (EPI == 0) {
#pragma unroll
    for (int i = 0; i < 4; ++i) {
      const int gr = m0 + wm + i * 16 + lhi * 4;
#pragma unroll
      for (int j = 0; j < 4; ++j) {
        const int gc = n0 + wn + j * 16 + l15;
        const float bv = bias ? bias[gc] : 0.f;
#pragma unroll
        for (int rr = 0; rr < 4; ++rr)
          ((float*)C)[(size_t)(gr + rr) * N + gc] = acc[i][j][rr] + bv;
      }
    }
  } else if (EPI == 3) {
#pragma unroll
    for (int i = 0; i < 4; ++i) {
      const int gr = m0 + wm + i * 16 + lhi * 4;
#pragma unroll
      for (int j = 0; j < 4; ++j) {
        const int gc = n0 + wn + j * 16 + l15;
        const float bv = bias[gc];
#pragma unroll
        for (int rr = 0; rr < 4; ++rr)
          ((u16*)C)[(size_t)(gr + rr) * N + gc] = f2b(tanhf(acc[i][j][rr] + bv));
      }
    }
  } else {
    float bj[4];
#pragma unroll
    for (int j = 0; j < 4; ++j) bj[j] = bias[n0 + wn + j * 16 + l15];
    const int pc = bx * 2 + (wn ? 1 : 0);
#pragma unroll
    for (int i = 0; i < 4; ++i) {
#pragma unroll
      for (int rr = 0; rr < 4; ++rr) {
        float v0 = acc[i][0][rr] + bj[0];
        float v1 = acc[i][1][rr] + bj[1];
        float v2 = acc[i][2][rr] + bj[2];
        float v3 = acc[i][3][rr] + bj[3];
        float m = fmaxf(fmaxf(v0, v1), fmaxf(v2, v3));
#pragma unroll
        for (int d = 1; d < 16; d <<= 1) m = fmaxf(m, __shfl_xor(m, d, 64));
        float s = __expf(v0 - m) + __expf(v1 - m) + __expf(v2 - m) + __expf(v3 - m);
#pragma unroll
        for (int d = 1; d < 16; d <<= 1) s += __shfl_xor(s, d, 64);
        if (l15 == 0) {
          const int grow = m0 + wm + i * 16 + lhi * 4 + rr;
          pmax[(size_t)grow * ncols + pc] = m;
          psum[(size_t)grow * ncols + pc] = s;
        }
      }
    }
  }
}

// ---- persistent encoder: 64 blocks x 256 thr, block owns 16 h-cols.
// W slice 128 KB LDS (XOR-swizzled); c in registers; h handoff via relaxed
// write-through agent atomics. Flag scheme (de-hotspotted): flags[consumer][
// producer] int, 256B per consumer row. Producer's 64 threads store its column
// across all consumer rows once per step (64 distinct lines, parallel);
// consumer wave0 spins ONLY on its private row -> no cross-block poll
// contention at the coherence point.
__global__ __launch_bounds__(256, 1)
void k_enc_all(const u16* __restrict__ Wb, const u16* __restrict__ gx,
               const float* __restrict__ b_ih, const float* __restrict__ b_hh,
               u16* __restrict__ hxl, float* __restrict__ c_out, int* flags) {
  __shared__ __align__(16) u16 Ws[64 * 1024];  // 128 KB, byte-XOR swizzled
  __shared__ float Gs[64 * 65];
  __shared__ float bsum[64];
  const int tid = threadIdx.x;
  const int wave = tid >> 6, lane = tid & 63;
  const int l15 = lane & 15, lhi = lane >> 4;
  const int c0 = blockIdx.x * 16;
  const int cb = tid >> 2, cq = tid & 3;
  const int rot = blockIdx.x & 31;

  for (int i = tid; i < 64 * 128; i += 256) {
    const int r = i >> 7, ck = i & 127;
    const int grow = (r >> 4) * Hh + c0 + (r & 15);
    const int bo = (ck * 16) ^ ((r & 7) << 4);
    *(bf16x8*)((char*)Ws + r * 2048 + bo) = *(const bf16x8*)(Wb + (size_t)grow * Hh + ck * 8);
  }
  if (tid < 64) {
    const int col = (tid >> 4) * Hh + c0 + (tid & 15);
    bsum[tid] = b_ih[col] + b_hh[col];
  }
  float creg[4] = {0.f, 0.f, 0.f, 0.f};
  __syncthreads();

  for (int s = 0; s < 64; ++s) {
    // x-gates prefetch (bf16, 4 per gate) — independent of h
    u64 graw[4];
#pragma unroll
    for (int g = 0; g < 4; ++g)
      graw[g] = *(const u64*)(gx + (size_t)(s * 64 + cb) * NT4 + g * Hh + c0 + cq * 4);

    f32x4 acc[4] = {};
    if (s > 0) {
      if (wave == 0) {
        for (;;) {
          const int f = AL32(flags + blockIdx.x * 64 + lane);  // private row
          if (__all(f >= s)) break;
          __builtin_amdgcn_s_sleep(1);
        }
      }
      __syncthreads();
      const u64* apw = (const u64*)(hxl + ((size_t)(s - 1) * 64 + wave * 16 + l15) * Hh);
      const char* wsb = (const char*)Ws;
      const int xr = (l15 & 7) << 4;
#pragma unroll 8
      for (int i = 0; i < 32; ++i) {
        const int kf = (i + rot) & 31;
        const int k = kf * 32 + lhi * 8;
        const u64 ua = AL(apw + (k >> 2));
        const u64 ub = AL(apw + (k >> 2) + 1);
        union { u64 qq[2]; bf16x8 v; } cv;
        cv.qq[0] = ua; cv.qq[1] = ub;
        const int kb = (k * 2) ^ xr;
#pragma unroll
        for (int nt = 0; nt < 4; ++nt)
          acc[nt] = MFMA(cv.v, *(const bf16x8*)(wsb + (nt * 16 + l15) * 2048 + kb), acc[nt]);
      }
    }
#pragma unroll
    for (int nt = 0; nt < 4; ++nt)
#pragma unroll
      for (int r = 0; r < 4; ++r)
        Gs[(wave * 16 + lhi * 4 + r) * 65 + nt * 16 + l15] = acc[nt][r];
    __syncthreads();
    {
      const float* gsrow = Gs + cb * 65;
      u64 pk = 0;
#pragma unroll
      for (int j = 0; j < 4; ++j) {
        const int col = cq * 4 + j;
        const float gi = gsrow[col]      + b2f((u16)(graw[0] >> (16 * j))) + bsum[col];
        const float gf = gsrow[16 + col] + b2f((u16)(graw[1] >> (16 * j))) + bsum[16 + col];
        const float gg = gsrow[32 + col] + b2f((u16)(graw[2] >> (16 * j))) + bsum[32 + col];
        const float go = gsrow[48 + col] + b2f((u16)(graw[3] >> (16 * j))) + bsum[48 + col];
        const float cn = sigf(gf) * creg[j] + sigf(gi) * tanhf(gg);
        const float hv = sigf(go) * tanhf(cn);
        creg[j] = cn;
        pk |= (u64)f2b(hv) << (16 * j);
      }
      AS((u64*)(hxl + ((size_t)s * 64 + cb) * Hh + c0 + cq * 4), pk);
    }
    __syncthreads();  // drains vmcnt(0): h stores durable at coherence point
    if (tid < ENC_NBLK)
      AS32(flags + tid * 64 + blockIdx.x, s + 1);  // fan-out to private rows
  }
#pragma unroll
  for (int j = 0; j < 4; ++j)
    c_out[cb * Hh + c0 + cq * 4 + j] = creg[j];
}

// ---- decoder cell (vectorized x4): gates = G_bf16[r] + dbase[b] + b_ih + b_hh
__global__ void k_dec_cell(const u16* __restrict__ G, const float* __restrict__ dbase,
                           const float* __restrict__ cT, const float* __restrict__ b_ih,
                           const float* __restrict__ b_hh, u16* __restrict__ Acat) {
  const int idx = blockIdx.x * 256 + threadIdx.x;
  const int r = idx >> 8, c4 = (idx & 255) * 4;
  if (r >= RD) return;
  const int b = r & 63;
  u64 graw[4]; f32x4 dv[4], bi[4], bh[4];
#pragma unroll
  for (int g = 0; g < 4; ++g) {
    graw[g] = *(const u64*)(G + (size_t)r * NT4 + g * Hh + c4);
    dv[g] = *(const f32x4*)(dbase + (size_t)b * NT4 + g * Hh + c4);
    bi[g] = *(const f32x4*)(b_ih + g * Hh + c4);
    bh[g] = *(const f32x4*)(b_hh + g * Hh + c4);
  }
  const f32x4 cv4 = *(const f32x4*)(cT + b * Hh + c4);
  u64 pk = 0;
#pragma unroll
  for (int j = 0; j < 4; ++j) {
    const float gi = b2f((u16)(graw[0] >> (16 * j))) + dv[0][j] + bi[0][j] + bh[0][j];
    const float gf = b2f((u16)(graw[1] >> (16 * j))) + dv[1][j] + bi[1][j] + bh[1][j];
    const float gg = b2f((u16)(graw[2] >> (16 * j))) + dv[2][j] + bi[2][j] + bh[2][j];
    const float go = b2f((u16)(graw[3] >> (16 * j))) + dv[3][j] + bi[3][j] + bh[3][j];
    const float cn = sigf(gf) * cv4[j] + sigf(gi) * tanhf(gg);
    const float hv = sigf(go) * tanhf(cn);
    pk |= (u64)f2b(hv) << (16 * j);
  }
  *(u64*)(Acat + (size_t)r * 2048 + Hh + c4) = pk;
}

// ---- fused attention per (t,b): scores + masked softmax + content -> A_cat[:, :H]
__global__ __launch_bounds__(256)
void k_attn(u16* Acat, const u16* __restrict__ hxl, const int* __restrict__ src) {
  __shared__ float qs[Hh];
  __shared__ float sc[Ss];
  const int r = blockIdx.x;
  const int b = r & 63;
  const int tid = threadIdx.x, wave = tid >> 6, lane = tid & 63;
  for (int h = tid; h < Hh; h += 256) qs[h] = b2f(Acat[(size_t)r * 2048 + Hh + h]);
  __syncthreads();
  for (int sub = 0; sub < 16; ++sub) {
    const int ss = wave * 16 + sub;
    const ushort4* hp4 = (const ushort4*)(hxl + ((size_t)ss * Bb + b) * Hh);
    float p = 0.f;
#pragma unroll
    for (int q = 0; q < 4; ++q) {
      const int i4 = lane + 64 * q;
      const ushort4 v = hp4[i4];
      p += qs[i4 * 4 + 0] * b2f(v.x) + qs[i4 * 4 + 1] * b2f(v.y)
         + qs[i4 * 4 + 2] * b2f(v.z) + qs[i4 * 4 + 3] * b2f(v.w);
    }
#pragma unroll
    for (int d = 1; d < 64; d <<= 1) p += __shfl_xor(p, d, 64);
    if (lane == 0) sc[ss] = (src[b * 64 + ss] != 0) ? p : -INFINITY;
  }
  __syncthreads();
  if (wave == 0) {
    const float v = sc[lane];
    float m = v;
#pragma unroll
    for (int d = 1; d < 64; d <<= 1) m = fmaxf(m, __shfl_xor(m, d, 64));
    const float e = __expf(v - m);
    float ssum = e;
#pragma unroll
    for (int d = 1; d < 64; d <<= 1) ssum += __shfl_xor(ssum, d, 64);
    sc[lane] = e / ssum;
  }
  __syncthreads();
  float4 a4 = {0.f, 0.f, 0.f, 0.f};
  for (int s2 = 0; s2 < 64; ++s2) {
    const float a = sc[s2];
    const ushort4 v = *(const ushort4*)(hxl + ((size_t)s2 * Bb + b) * Hh + tid * 4);
    a4.x += a * b2f(v.x); a4.y += a * b2f(v.y);
    a4.z += a * b2f(v.z); a4.w += a * b2f(v.w);
  }
  u16* dst = Acat + (size_t)r * 2048 + tid * 4;
  dst[0] = f2b(a4.x); dst[1] = f2b(a4.y); dst[2] = f2b(a4.z); dst[3] = f2b(a4.w);
}

// ---- merged: lse combine + target logit -> nll[r] = lse - logit_target ----
__global__ void k_lsetl(const float* __restrict__ pmax, const float* __restrict__ psum,
                        const u16* __restrict__ hx_att_b, const int* __restrict__ target,
                        const float* __restrict__ W, const float* __restrict__ bo,
                        float* __restrict__ nll, int ncols) {
  const int r = blockIdx.x * 4 + (threadIdx.x >> 6);
  const int lane = threadIdx.x & 63;
  if (r >= RD) return;
  float m = -INFINITY;
  for (int i = lane; i < ncols; i += 64) m = fmaxf(m, pmax[(size_t)r * ncols + i]);
#pragma unroll
  for (int d = 1; d < 64; d <<= 1) m = fmaxf(m, __shfl_xor(m, d, 64));
  float s = 0.f;
  for (int i = lane; i < ncols; i += 64)
    s += psum[(size_t)r * ncols + i] * __expf(pmax[(size_t)r * ncols + i] - m);
#pragma unroll
  for (int d = 1; d < 64; d <<= 1) s += __shfl_xor(s, d, 64);
  const int t = r >> 6, b = r & 63;
  const int w = target[b * 64 + t + 1];
  const u16* a = hx_att_b + (size_t)r * Hh;
  const float* wr = W + (size_t)w * Hh;
  float p = 0.f;
  for (int h = lane; h < Hh; h += 64) p += b2f(a[h]) * wr[h];
#pragma unroll
  for (int d = 1; d < 64; d <<= 1) p += __shfl_xor(p, d, 64);
  if (lane == 0) nll[r] = (m + logf(s)) - (p + bo[w]);
}

// ---- final reduction -> scalar loss
__global__ void k_final(const float* __restrict__ nll, const int* __restrict__ target,
                        float* __restrict__ out) {
  const int t = threadIdx.x;
  float ps = 0.f;
  if (t < 63) {
    float sn = 0.f, cnt = 0.f;
    for (int b = 0; b < 64; ++b) {
      const int r = t * 64 + b;
      const int w = target[b * 64 + t + 1];
      if (w != 0) { sn += nll[r]; cnt += 1.f; }
    }
    ps = sn / fmaxf(cnt, 1.f);
  }
#pragma unroll
  for (int d = 1; d < 64; d <<= 1) ps += __shfl_xor(ps, d, 64);
  if (t == 0) out[0] = ps;
}

extern "C" void kernel_launch(void* const* d_in, const int* in_sizes, int n_in,
                              void* d_out, int out_size, void* d_ws, size_t ws_size,
                              hipStream_t stream) {
  const int*   source   = (const int*)d_in[0];
  const int*   target   = (const int*)d_in[1];
  const float* emb_src  = (const float*)d_in[2];
  const float* emb_tgt  = (const float*)d_in[3];
  const float* W_ih_enc = (const float*)d_in[4];
  const float* W_hh_enc = (const float*)d_in[5];
  const float* b_ih_enc = (const float*)d_in[6];
  const float* b_hh_enc = (const float*)d_in[7];
  const float* W_ih_dec = (const float*)d_in[8];
  const float* W_hh_dec = (const float*)d_in[9];
  const float* b_ih_dec = (const float*)d_in[10];
  const float* b_hh_dec = (const float*)d_in[11];
  const float* W_att    = (const float*)d_in[12];
  const float* b_att    = (const float*)d_in[13];
  const float* W_out    = (const float*)d_in[14];
  const float* b_out    = (const float*)d_in[15];
  float* out = (float*)d_out;

  char* base = (char*)d_ws;
  size_t off = 0;
  auto alloc = [&](size_t bytes) -> void* {
    void* r = base + off; off += (bytes + 255) & ~(size_t)255; return r;
  };
  u16*   wb_ih_enc = (u16*)alloc((size_t)NT4 * Hh * 2);
  u16*   wb_hh_enc = (u16*)alloc((size_t)NT4 * Hh * 2);
  u16*   wb_ih_dec = (u16*)alloc((size_t)NT4 * Hh * 2);
  u16*   wb_hh_dec = (u16*)alloc((size_t)NT4 * Hh * 2);
  u16*   wb_att    = (u16*)alloc((size_t)Hh * 2048 * 2);
  u16*   wb_out    = (u16*)alloc((size_t)Vv * Hh * 2);
  u16*   x_src_b   = (u16*)alloc((size_t)RP * Hh * 2);
  u16*   x_dec_b   = (u16*)alloc((size_t)RP * Hh * 2);
  u16*   gates16   = (u16*)alloc((size_t)RP * NT4 * 2);
  u16*   gates_dec = (u16*)alloc((size_t)RP * NT4 * 2);
  u16*   hxl       = (u16*)alloc((size_t)Ss * Bb * Hh * 2);
  float* c_enc     = (float*)alloc((size_t)Bb * Hh * 4);
  float* dbase     = (float*)alloc((size_t)128 * NT4 * 4);
  u16*   Acat      = (u16*)alloc((size_t)RP * 2048 * 2);
  u16*   hx_att_b  = (u16*)alloc((size_t)RP * Hh * 2);
  float* pmax      = (float*)alloc((size_t)RP * 500 * 4);
  float* psum      = (float*)alloc((size_t)RP * 500 * 4);
  float* nll       = (float*)alloc((size_t)RD * 4);
  int*   flags     = (int*)alloc(ENC_NBLK * ENC_NBLK * 4);

  if (off > ws_size) { k_fail<<<1, 1, 0, stream>>>(out); return; }

  // weights -> bf16
  k_cvt<<<2048, 256, 0, stream>>>(W_ih_enc, wb_ih_enc, NT4 * Hh / 4);
  k_cvt<<<2048, 256, 0, stream>>>(W_hh_enc, wb_hh_enc, NT4 * Hh / 4);
  k_cvt<<<2048, 256, 0, stream>>>(W_ih_dec, wb_ih_dec, NT4 * Hh / 4);
  k_cvt<<<2048, 256, 0, stream>>>(W_hh_dec, wb_hh_dec, NT4 * Hh / 4);
  k_cvt<<<2048, 256, 0, stream>>>(W_att, wb_att, Hh * 2048 / 4);
  k_cvt<<<2048, 256, 0, stream>>>(W_out, wb_out, Vv * Hh / 4);

  hipMemsetAsync(flags, 0, ENC_NBLK * ENC_NBLK * 4, stream);

  // embedding gathers
  k_gather<<<RP, 256, 0, stream>>>(source, emb_src, x_src_b, 64);
  k_gather<<<RP, 256, 0, stream>>>(target, emb_tgt, x_dec_b, 63);

  // encoder x-gates pre-GEMM (bf16), then persistent dataflow encoder
  k_pre<<<1024, 256, 0, stream>>>(x_src_b, wb_ih_enc, gates16);
  k_enc_all<<<ENC_NBLK, 256, 0, stream>>>(wb_hh_enc, gates16, b_ih_enc, b_hh_enc,
                                          hxl, c_enc, flags);

  // decoder x-gates pre-GEMM (bf16) + hT base + cell
  k_pre<<<1024, 256, 0, stream>>>(x_dec_b, wb_ih_dec, gates_dec);
  k_gemm<0><<<dim3(32, 1), 256, 0, stream>>>(hxl + (size_t)63 * Bb * Hh, wb_hh_dec, dbase,
                                             64, NT4, Hh, nullptr, nullptr, nullptr, 0);
  k_dec_cell<<<RD, 256, 0, stream>>>(gates_dec, dbase, c_enc, b_ih_dec, b_hh_dec, Acat);

  // attention -> content into A_cat[:, :H]
  k_attn<<<RD, 256, 0, stream>>>(Acat, hxl, source);

  // hx_att_b = bf16(tanh(A_cat @ W_att^T + b_att))
  k_gemm<3><<<dim3(8, 32), 256, 0, stream>>>(Acat, wb_att, hx_att_b, RP, Hh, 2048,
                                             b_att, nullptr, nullptr, 0);

  // vocab GEMM with fused lse partials
  k_gemm<2><<<dim3(250, 32), 256, 0, stream>>>(hx_att_b, wb_out, nullptr, RP, Vv, Hh,
                                               b_out, pmax, psum, 500);
  k_lsetl<<<(RD + 3) / 4, 256, 0, stream>>>(pmax, psum, hx_att_b, target, W_out, b_out,
                                            nll, 500);
  k_final<<<1, 64, 0, stream>>>(nll, target, out);
}